// Round 5
// baseline (155.241 us; speedup 1.0000x reference)
//
#include <hip/hip_runtime.h>
#include <cstdint>

#define B_ 2
#define H_ 16
#define S_ 2048
#define DK_ 64
#define BH_ (B_*H_)
#define NQT 32    // 64-row q tiles

typedef __attribute__((ext_vector_type(8))) short short8;
typedef __attribute__((ext_vector_type(4))) short short4v;
typedef __attribute__((ext_vector_type(4))) float floatx4;

__device__ inline unsigned short f2bf(float f) {
  union { float f; unsigned u; } v; v.f = f;
  unsigned u = v.u;
  unsigned r = u + 0x7fffu + ((u >> 16) & 1u);   // RNE
  return (unsigned short)(r >> 16);
}

__device__ inline floatx4 mfma16(short4v a, short4v b, floatx4 c) {
#if __has_builtin(__builtin_amdgcn_mfma_f32_16x16x16bf16_1k)
  return __builtin_amdgcn_mfma_f32_16x16x16bf16_1k(a, b, c, 0, 0, 0);
#else
  asm("v_mfma_f32_16x16x16_bf16 %0, %1, %2, %0" : "+v"(c) : "v"(a), "v"(b));
  return c;
#endif
}

__device__ inline short4v u2s4(unsigned a, unsigned b) {
  union { unsigned u[2]; short4v s; } v;
  v.u[0] = a; v.u[1] = b;
  return v.s;
}

// -------- prologue: K -> bf16 rows; V -> bf16 transposed [bh][d][s-permuted] --------
// V^T s-permutation within each 128-block: pos = 32*t2 + 8*q + 4*h + j holds
// s = 32*t2 + 16*h + 4*q + j  -> PV A-frags become single b128 reads (2 slices/read).
__global__ __launch_bounds__(256) void conv_kv(const float* __restrict__ K,
                                               const float* __restrict__ V,
                                               unsigned short* __restrict__ Kb,
                                               unsigned short* __restrict__ Vb) {
  __shared__ __align__(16) unsigned short t[64 * 80];
  const int bh = blockIdx.y, s0 = blockIdx.x * 64;
  const int row = threadIdx.x >> 2, cp = threadIdx.x & 3;

  { // K: straight convert, coalesced
    const float* src = K + ((size_t)(bh * S_ + s0 + row)) * DK_ + cp * 16;
    unsigned short* dst = Kb + ((size_t)(bh * S_ + s0 + row)) * DK_ + cp * 16;
    #pragma unroll
    for (int h = 0; h < 2; ++h) {
      float4 a = *(const float4*)(src + h * 8);
      float4 b = *(const float4*)(src + h * 8 + 4);
      uint4 st;
      st.x = (unsigned)f2bf(a.x) | ((unsigned)f2bf(a.y) << 16);
      st.y = (unsigned)f2bf(a.z) | ((unsigned)f2bf(a.w) << 16);
      st.z = (unsigned)f2bf(b.x) | ((unsigned)f2bf(b.y) << 16);
      st.w = (unsigned)f2bf(b.z) | ((unsigned)f2bf(b.w) << 16);
      *(uint4*)(dst + h * 8) = st;
    }
  }
  { // V: transpose via LDS; permuted, fully-coalesced uint4 stores
    const float* src = V + ((size_t)(bh * S_ + s0 + row)) * DK_ + cp * 16;
    #pragma unroll
    for (int j4 = 0; j4 < 4; ++j4) {
      float4 a = *(const float4*)(src + j4 * 4);
      int c = cp * 16 + j4 * 4;
      t[(c + 0) * 80 + row] = f2bf(a.x);
      t[(c + 1) * 80 + row] = f2bf(a.y);
      t[(c + 2) * 80 + row] = f2bf(a.z);
      t[(c + 3) * 80 + row] = f2bf(a.w);
    }
    __syncthreads();
    // output-major: thread owns 16 contiguous permuted positions of d-row `row`
    unsigned short* dst = Vb + ((size_t)(bh * DK_ + row)) * S_ + s0 + cp * 16;
    #pragma unroll
    for (int g = 0; g < 2; ++g) {
      const int pg = 2 * cp + g;                 // 8-pos group index
      const int t2r = pg >> 2, q = pg & 3;       // pos = 32t2+8q+4h+j <- s = 32t2+16h+4q+j
      uint2 a = *(const uint2*)&t[row * 80 + 32 * t2r + 4 * q];
      uint2 b = *(const uint2*)&t[row * 80 + 32 * t2r + 16 + 4 * q];
      uint4 st = {a.x, a.y, b.x, b.y};
      *(uint4*)(dst + g * 8) = st;
    }
  }
}

// -------- flash attention: S^T form, register-P, single-buffer tiles, 4 blocks/CU ----
__global__ __launch_bounds__(256, 4)
void fa_kernel(const float* __restrict__ Q, const unsigned short* __restrict__ Kb,
               const unsigned short* __restrict__ Vb, float* __restrict__ Out) {
  // Kt: 128 s-rows x 64 d (8 chunks/row, swizzle p=c^(row&7))
  // Vt: 64 d-rows x 128 s-permuted (16 chunks/row, swizzle p=c^(row&15))
  __shared__ __align__(16) unsigned short Kt[8192];   // 16 KB
  __shared__ __align__(16) unsigned short Vt[8192];   // 16 KB

  const int tid  = threadIdx.x;
  const int wave = tid >> 6;
  const int lane = tid & 63;
  const int quad = lane >> 4;
  const int l16  = lane & 15;
  const int wq   = wave & 1;   // q-strip half (32 rows)
  const int ws   = wave >> 1;  // s-half (64 of 128)

  // XCD-aware decode: bh in low bits (same bh -> same XCD L2); big q-tiles first
  const int id = blockIdx.x;
  const int bh = (id & 7) | (((id >> 3) & 3) << 3);
  const int qt = NQT - 1 - (id >> 5);

  const float SCL = 0.125f * 1.44269504088896340736f;  // 1/sqrt(64)*log2(e), folded into Q

  // ---- Q fragments, B-operand of S^T=K*Q^T: lane n=q=l16, k=d=ks*32+quad*8+j
  short8 qf[4];   // [nq*2+ks]
  #pragma unroll
  for (int nq = 0; nq < 2; ++nq) {
    const float* p = Q + ((size_t)bh * S_ + qt * 64 + wq * 32 + nq * 16 + l16) * DK_ + quad * 8;
    #pragma unroll
    for (int ks = 0; ks < 2; ++ks) {
      float4 x = *(const float4*)(p + ks * 32);
      float4 y = *(const float4*)(p + ks * 32 + 4);
      short8 t;
      t[0]=(short)f2bf(x.x*SCL); t[1]=(short)f2bf(x.y*SCL); t[2]=(short)f2bf(x.z*SCL); t[3]=(short)f2bf(x.w*SCL);
      t[4]=(short)f2bf(y.x*SCL); t[5]=(short)f2bf(y.y*SCL); t[6]=(short)f2bf(y.z*SCL); t[7]=(short)f2bf(y.w*SCL);
      qf[nq * 2 + ks] = t;
    }
  }

  floatx4 Ot[4][2];            // O^T partials [dblk][nq]
  float ls[2] = {0.f, 0.f};
  #pragma unroll
  for (int d = 0; d < 4; ++d)
    #pragma unroll
    for (int nq = 0; nq < 2; ++nq) Ot[d][nq] = (floatx4){0,0,0,0};

  const int nkv = (qt >> 1) + 1;
  for (int kv = 0; kv < nkv; ++kv) {
    if (kv) __syncthreads();       // readers done before restage
    // ---- stage K,V tile (async 16B chunks, XOR-swizzled)
    #pragma unroll
    for (int rd = 0; rd < 4; ++rd) {
      const int cid = rd * 256 + wave * 64 + lane;
      {
        int row = cid >> 3, p = cid & 7, c = p ^ (row & 7);
        const unsigned short* g = Kb + (((size_t)bh * S_ + kv * 128 + row) << 6) + (c << 3);
        __builtin_amdgcn_global_load_lds(
            (const __attribute__((address_space(1))) void*)g,
            (__attribute__((address_space(3))) void*)&Kt[(rd * 4 + wave) * 512], 16, 0, 0);
      }
      {
        int row = cid >> 4, p = cid & 15, c = p ^ (row & 15);
        const unsigned short* g = Vb + (((size_t)bh * DK_ + row) << 11) + kv * 128 + (c << 3);
        __builtin_amdgcn_global_load_lds(
            (const __attribute__((address_space(1))) void*)g,
            (__attribute__((address_space(3))) void*)&Vt[(rd * 4 + wave) * 512], 16, 0, 0);
      }
    }
    __syncthreads();               // staging visible

    // ---- S^T = K Q^T : per-wave 64s x 32q
    const bool domask = (kv == nkv - 1);
    unsigned pk[4][2][2];          // [nt][nq][pair] packed bf16x2 exp'd scores
    #pragma unroll
    for (int nt = 0; nt < 4; ++nt) {
      const int row = ws * 64 + nt * 16 + l16;     // s-row in Kt
      floatx4 s0 = (floatx4){0,0,0,0}, s1 = (floatx4){0,0,0,0};
      #pragma unroll
      for (int ks = 0; ks < 2; ++ks) {
        const int p = (ks * 4 + quad) ^ (row & 7);
        const short8 ak = *(const short8*)&Kt[row * 64 + p * 8];
        s0 = __builtin_amdgcn_mfma_f32_16x16x32_bf16(ak, qf[ks],     s0, 0, 0, 0);
        s1 = __builtin_amdgcn_mfma_f32_16x16x32_bf16(ak, qf[2 + ks], s1, 0, 0, 0);
      }
      if (domask) {   // S^T: lane holds q=l16(+16nq), s=quad*4+r
        const int sb  = kv * 128 + ws * 64 + nt * 16 + quad * 4;
        const int q0r = qt * 64 + wq * 32 + l16;
        #pragma unroll
        for (int r = 0; r < 4; ++r) {
          if (sb + r > q0r)      s0[r] = -INFINITY;
          if (sb + r > q0r + 16) s1[r] = -INFINITY;
        }
      }
      #pragma unroll
      for (int nq = 0; nq < 2; ++nq) {
        const floatx4 sv = nq ? s1 : s0;
        float e0 = __builtin_amdgcn_exp2f(sv[0]);
        float e1 = __builtin_amdgcn_exp2f(sv[1]);
        float e2 = __builtin_amdgcn_exp2f(sv[2]);
        float e3 = __builtin_amdgcn_exp2f(sv[3]);
        ls[nq] += (e0 + e1) + (e2 + e3);
        pk[nt][nq][0] = __builtin_amdgcn_perm(__float_as_uint(e1) + 0x8000u,
                                              __float_as_uint(e0) + 0x8000u, 0x07060302u);
        pk[nt][nq][1] = __builtin_amdgcn_perm(__float_as_uint(e3) + 0x8000u,
                                              __float_as_uint(e2) + 0x8000u, 0x07060302u);
      }
    }
    // ---- O^T += V^T P^T : P fed from registers (x16 B-layout == C-layout)
    #pragma unroll
    for (int dblk = 0; dblk < 4; ++dblk) {
      const int row = dblk * 16 + l16;             // d-row in Vt
      #pragma unroll
      for (int tt = 0; tt < 2; ++tt) {
        const int p = ((ws * 2 + tt) * 4 + quad) ^ l16;
        const short8 v8 = *(const short8*)&Vt[row * 128 + p * 8];
        const short4v vlo = __builtin_shufflevector(v8, v8, 0, 1, 2, 3);
        const short4v vhi = __builtin_shufflevector(v8, v8, 4, 5, 6, 7);
        #pragma unroll
        for (int nq = 0; nq < 2; ++nq) {
          Ot[dblk][nq] = mfma16(vlo, u2s4(pk[2*tt  ][nq][0], pk[2*tt  ][nq][1]), Ot[dblk][nq]);
          Ot[dblk][nq] = mfma16(vhi, u2s4(pk[2*tt+1][nq][0], pk[2*tt+1][nq][1]), Ot[dblk][nq]);
        }
      }
    }
  }
  __syncthreads();   // main loop done before LDS reuse

  // ---- epilogue: l over quads, then cross-ws O^T/l reduction through LDS
  #pragma unroll
  for (int nq = 0; nq < 2; ++nq) {
    ls[nq] += __shfl_xor(ls[nq], 16);
    ls[nq] += __shfl_xor(ls[nq], 32);
  }
  float* OP = (float*)&Kt[0];   // 64 rows x 64 d = 16 KB
  float* LP = (float*)&Vt[0];   // 64 f32
  if (ws == 1) {
    #pragma unroll
    for (int nq = 0; nq < 2; ++nq) {
      const int rowi = (wq * 2 + nq) * 16 + l16;
      #pragma unroll
      for (int dblk = 0; dblk < 4; ++dblk) {
        const int c2 = (dblk * 4 + quad) ^ (l16 & 12);
        *(floatx4*)&OP[rowi * 64 + c2 * 4] = Ot[dblk][nq];
      }
      if (quad == 0) LP[rowi] = ls[nq];
    }
  }
  __syncthreads();
  if (ws == 0) {
    #pragma unroll
    for (int nq = 0; nq < 2; ++nq) {
      const int rowi = (wq * 2 + nq) * 16 + l16;
      const float inv = 1.0f / (ls[nq] + LP[rowi]);
      float* og = Out + ((size_t)bh * S_ + qt * 64 + wq * 32 + nq * 16 + l16) * DK_;
      #pragma unroll
      for (int dblk = 0; dblk < 4; ++dblk) {
        const int c2 = (dblk * 4 + quad) ^ (l16 & 12);
        floatx4 tot = Ot[dblk][nq] + *(const floatx4*)&OP[rowi * 64 + c2 * 4];
        tot *= inv;
        *(floatx4*)(og + dblk * 16 + quad * 4) = tot;
      }
    }
  }
}

extern "C" void kernel_launch(void* const* d_in, const int* in_sizes, int n_in,
                              void* d_out, int out_size, void* d_ws, size_t ws_size,
                              hipStream_t stream) {
  const float* Q = (const float*)d_in[0];
  const float* K = (const float*)d_in[1];
  const float* V = (const float*)d_in[2];
  // d_in[3] = d_k (=64), d_in[4] = causal tril mask (applied analytically)
  float* Out = (float*)d_out;
  unsigned short* Kb = (unsigned short*)d_ws;                    // 8.4 MB
  unsigned short* Vb = Kb + (size_t)BH_ * S_ * DK_;              // 8.4 MB
  conv_kv<<<dim3(S_ / 64, BH_), 256, 0, stream>>>(K, V, Kb, Vb);
  fa_kernel<<<dim3(NQT * BH_), 256, 0, stream>>>(Q, Kb, Vb, Out);
}

// Round 6
// 140.619 us; speedup vs baseline: 1.1040x; 1.1040x over previous
//
#include <hip/hip_runtime.h>
#include <cstdint>

#define B_ 2
#define H_ 16
#define S_ 2048
#define DK_ 64
#define BH_ (B_*H_)
#define NQT 32    // 64-row q tiles

typedef __attribute__((ext_vector_type(8))) short short8;
typedef __attribute__((ext_vector_type(4))) short short4v;
typedef __attribute__((ext_vector_type(4))) float floatx4;

__device__ inline unsigned short f2bf(float f) {
  union { float f; unsigned u; } v; v.f = f;
  unsigned u = v.u;
  unsigned r = u + 0x7fffu + ((u >> 16) & 1u);   // RNE
  return (unsigned short)(r >> 16);
}

__device__ inline floatx4 mfma16(short4v a, short4v b, floatx4 c) {
#if __has_builtin(__builtin_amdgcn_mfma_f32_16x16x16bf16_1k)
  return __builtin_amdgcn_mfma_f32_16x16x16bf16_1k(a, b, c, 0, 0, 0);
#else
  asm("v_mfma_f32_16x16x16_bf16 %0, %1, %2, %0" : "+v"(c) : "v"(a), "v"(b));
  return c;
#endif
}

__device__ inline short4v u2s4(unsigned a, unsigned b) {
  union { unsigned u[2]; short4v s; } v;
  v.u[0] = a; v.u[1] = b;
  return v.s;
}

// -------- prologue: K -> bf16 rows; V -> bf16 transposed [bh][d][s-permuted] --------
// V^T s-permutation within each 128-block: pos = 32*t2 + 8*q + 4*h + j holds
// s = 32*t2 + 16*h + 4*q + j  -> PV A-frags become single b128 reads (2 slices/read).
__global__ __launch_bounds__(256) void conv_kv(const float* __restrict__ K,
                                               const float* __restrict__ V,
                                               unsigned short* __restrict__ Kb,
                                               unsigned short* __restrict__ Vb) {
  __shared__ __align__(16) unsigned short t[64 * 80];
  const int bh = blockIdx.y, s0 = blockIdx.x * 64;
  const int row = threadIdx.x >> 2, cp = threadIdx.x & 3;

  { // K: straight convert, coalesced
    const float* src = K + ((size_t)(bh * S_ + s0 + row)) * DK_ + cp * 16;
    unsigned short* dst = Kb + ((size_t)(bh * S_ + s0 + row)) * DK_ + cp * 16;
    #pragma unroll
    for (int h = 0; h < 2; ++h) {
      float4 a = *(const float4*)(src + h * 8);
      float4 b = *(const float4*)(src + h * 8 + 4);
      uint4 st;
      st.x = (unsigned)f2bf(a.x) | ((unsigned)f2bf(a.y) << 16);
      st.y = (unsigned)f2bf(a.z) | ((unsigned)f2bf(a.w) << 16);
      st.z = (unsigned)f2bf(b.x) | ((unsigned)f2bf(b.y) << 16);
      st.w = (unsigned)f2bf(b.z) | ((unsigned)f2bf(b.w) << 16);
      *(uint4*)(dst + h * 8) = st;
    }
  }
  { // V: transpose via LDS; permuted, fully-coalesced uint4 stores
    const float* src = V + ((size_t)(bh * S_ + s0 + row)) * DK_ + cp * 16;
    #pragma unroll
    for (int j4 = 0; j4 < 4; ++j4) {
      float4 a = *(const float4*)(src + j4 * 4);
      int c = cp * 16 + j4 * 4;
      t[(c + 0) * 80 + row] = f2bf(a.x);
      t[(c + 1) * 80 + row] = f2bf(a.y);
      t[(c + 2) * 80 + row] = f2bf(a.z);
      t[(c + 3) * 80 + row] = f2bf(a.w);
    }
    __syncthreads();
    // output-major: thread owns 16 contiguous permuted positions of d-row `row`
    unsigned short* dst = Vb + ((size_t)(bh * DK_ + row)) * S_ + s0 + cp * 16;
    #pragma unroll
    for (int g = 0; g < 2; ++g) {
      const int pg = 2 * cp + g;                 // 8-pos group index
      const int t2r = pg >> 2, q = pg & 3;       // pos = 32t2+8q+4h+j <- s = 32t2+16h+4q+j
      uint2 a = *(const uint2*)&t[row * 80 + 32 * t2r + 4 * q];
      uint2 b = *(const uint2*)&t[row * 80 + 32 * t2r + 16 + 4 * q];
      uint4 st = {a.x, a.y, b.x, b.y};
      *(uint4*)(dst + g * 8) = st;
    }
  }
}

// -------- flash attention: S^T form, register-P, single-buffer tiles ----
// NOTE: launch_bounds min-waves MUST stay 2: requesting 4 forces the allocator
// to the 64-VGPR tier and this ~100-VGPR kernel spills (R5: WRITE_SIZE 16->61MB,
// 44->64us). LDS=32KB + ~128 VGPR already allow 4 blocks/CU naturally.
__global__ __launch_bounds__(256, 2)
void fa_kernel(const float* __restrict__ Q, const unsigned short* __restrict__ Kb,
               const unsigned short* __restrict__ Vb, float* __restrict__ Out) {
  // Kt: 128 s-rows x 64 d (8 chunks/row, swizzle p=c^(row&7))
  // Vt: 64 d-rows x 128 s-permuted (16 chunks/row, swizzle p=c^(row&15))
  __shared__ __align__(16) unsigned short Kt[8192];   // 16 KB
  __shared__ __align__(16) unsigned short Vt[8192];   // 16 KB

  const int tid  = threadIdx.x;
  const int wave = tid >> 6;
  const int lane = tid & 63;
  const int quad = lane >> 4;
  const int l16  = lane & 15;
  const int wq   = wave & 1;   // q-strip half (32 rows)
  const int ws   = wave >> 1;  // s-half (64 of 128)

  // XCD-aware decode: bh in low bits (same bh -> same XCD L2); big q-tiles first
  const int id = blockIdx.x;
  const int bh = (id & 7) | (((id >> 3) & 3) << 3);
  const int qt = NQT - 1 - (id >> 5);

  const float SCL = 0.125f * 1.44269504088896340736f;  // 1/sqrt(64)*log2(e), folded into Q

  // ---- Q fragments, B-operand of S^T=K*Q^T: lane n=q=l16, k=d=ks*32+quad*8+j
  short8 qf[4];   // [nq*2+ks]
  #pragma unroll
  for (int nq = 0; nq < 2; ++nq) {
    const float* p = Q + ((size_t)bh * S_ + qt * 64 + wq * 32 + nq * 16 + l16) * DK_ + quad * 8;
    #pragma unroll
    for (int ks = 0; ks < 2; ++ks) {
      float4 x = *(const float4*)(p + ks * 32);
      float4 y = *(const float4*)(p + ks * 32 + 4);
      short8 t;
      t[0]=(short)f2bf(x.x*SCL); t[1]=(short)f2bf(x.y*SCL); t[2]=(short)f2bf(x.z*SCL); t[3]=(short)f2bf(x.w*SCL);
      t[4]=(short)f2bf(y.x*SCL); t[5]=(short)f2bf(y.y*SCL); t[6]=(short)f2bf(y.z*SCL); t[7]=(short)f2bf(y.w*SCL);
      qf[nq * 2 + ks] = t;
    }
  }

  floatx4 Ot[4][2];            // O^T partials [dblk][nq]
  float ls[2] = {0.f, 0.f};
  #pragma unroll
  for (int d = 0; d < 4; ++d)
    #pragma unroll
    for (int nq = 0; nq < 2; ++nq) Ot[d][nq] = (floatx4){0,0,0,0};

  const int nkv = (qt >> 1) + 1;
  for (int kv = 0; kv < nkv; ++kv) {
    if (kv) __syncthreads();       // readers done before restage
    // ---- stage K,V tile (async 16B chunks, XOR-swizzled)
    #pragma unroll
    for (int rd = 0; rd < 4; ++rd) {
      const int cid = rd * 256 + wave * 64 + lane;
      {
        int row = cid >> 3, p = cid & 7, c = p ^ (row & 7);
        const unsigned short* g = Kb + (((size_t)bh * S_ + kv * 128 + row) << 6) + (c << 3);
        __builtin_amdgcn_global_load_lds(
            (const __attribute__((address_space(1))) void*)g,
            (__attribute__((address_space(3))) void*)&Kt[(rd * 4 + wave) * 512], 16, 0, 0);
      }
      {
        int row = cid >> 4, p = cid & 15, c = p ^ (row & 15);
        const unsigned short* g = Vb + (((size_t)bh * DK_ + row) << 11) + kv * 128 + (c << 3);
        __builtin_amdgcn_global_load_lds(
            (const __attribute__((address_space(1))) void*)g,
            (__attribute__((address_space(3))) void*)&Vt[(rd * 4 + wave) * 512], 16, 0, 0);
      }
    }
    __syncthreads();               // staging visible

    // ---- S^T = K Q^T : per-wave 64s x 32q
    const bool domask = (kv == nkv - 1);
    unsigned pk[4][2][2];          // [nt][nq][pair] packed bf16x2 exp'd scores
    #pragma unroll
    for (int nt = 0; nt < 4; ++nt) {
      const int row = ws * 64 + nt * 16 + l16;     // s-row in Kt
      floatx4 s0 = (floatx4){0,0,0,0}, s1 = (floatx4){0,0,0,0};
      #pragma unroll
      for (int ks = 0; ks < 2; ++ks) {
        const int p = (ks * 4 + quad) ^ (row & 7);
        const short8 ak = *(const short8*)&Kt[row * 64 + p * 8];
        s0 = __builtin_amdgcn_mfma_f32_16x16x32_bf16(ak, qf[ks],     s0, 0, 0, 0);
        s1 = __builtin_amdgcn_mfma_f32_16x16x32_bf16(ak, qf[2 + ks], s1, 0, 0, 0);
      }
      if (domask) {   // S^T: lane holds q=l16(+16nq), s=quad*4+r
        const int sb  = kv * 128 + ws * 64 + nt * 16 + quad * 4;
        const int q0r = qt * 64 + wq * 32 + l16;
        #pragma unroll
        for (int r = 0; r < 4; ++r) {
          if (sb + r > q0r)      s0[r] = -INFINITY;
          if (sb + r > q0r + 16) s1[r] = -INFINITY;
        }
      }
      #pragma unroll
      for (int nq = 0; nq < 2; ++nq) {
        const floatx4 sv = nq ? s1 : s0;
        float e0 = __builtin_amdgcn_exp2f(sv[0]);
        float e1 = __builtin_amdgcn_exp2f(sv[1]);
        float e2 = __builtin_amdgcn_exp2f(sv[2]);
        float e3 = __builtin_amdgcn_exp2f(sv[3]);
        ls[nq] += (e0 + e1) + (e2 + e3);
        pk[nt][nq][0] = __builtin_amdgcn_perm(__float_as_uint(e1) + 0x8000u,
                                              __float_as_uint(e0) + 0x8000u, 0x07060302u);
        pk[nt][nq][1] = __builtin_amdgcn_perm(__float_as_uint(e3) + 0x8000u,
                                              __float_as_uint(e2) + 0x8000u, 0x07060302u);
      }
    }
    // ---- O^T += V^T P^T : P fed from registers (x16 B-layout == C-layout)
    #pragma unroll
    for (int dblk = 0; dblk < 4; ++dblk) {
      const int row = dblk * 16 + l16;             // d-row in Vt
      #pragma unroll
      for (int tt = 0; tt < 2; ++tt) {
        const int p = ((ws * 2 + tt) * 4 + quad) ^ l16;
        const short8 v8 = *(const short8*)&Vt[row * 128 + p * 8];
        const short4v vlo = __builtin_shufflevector(v8, v8, 0, 1, 2, 3);
        const short4v vhi = __builtin_shufflevector(v8, v8, 4, 5, 6, 7);
        #pragma unroll
        for (int nq = 0; nq < 2; ++nq) {
          Ot[dblk][nq] = mfma16(vlo, u2s4(pk[2*tt  ][nq][0], pk[2*tt  ][nq][1]), Ot[dblk][nq]);
          Ot[dblk][nq] = mfma16(vhi, u2s4(pk[2*tt+1][nq][0], pk[2*tt+1][nq][1]), Ot[dblk][nq]);
        }
      }
    }
  }
  __syncthreads();   // main loop done before LDS reuse

  // ---- epilogue: l over quads, then cross-ws O^T/l reduction through LDS
  #pragma unroll
  for (int nq = 0; nq < 2; ++nq) {
    ls[nq] += __shfl_xor(ls[nq], 16);
    ls[nq] += __shfl_xor(ls[nq], 32);
  }
  float* OP = (float*)&Kt[0];   // 64 rows x 64 d = 16 KB
  float* LP = (float*)&Vt[0];   // 64 f32
  if (ws == 1) {
    #pragma unroll
    for (int nq = 0; nq < 2; ++nq) {
      const int rowi = (wq * 2 + nq) * 16 + l16;
      #pragma unroll
      for (int dblk = 0; dblk < 4; ++dblk) {
        const int c2 = (dblk * 4 + quad) ^ (l16 & 12);
        *(floatx4*)&OP[rowi * 64 + c2 * 4] = Ot[dblk][nq];
      }
      if (quad == 0) LP[rowi] = ls[nq];
    }
  }
  __syncthreads();
  if (ws == 0) {
    #pragma unroll
    for (int nq = 0; nq < 2; ++nq) {
      const int rowi = (wq * 2 + nq) * 16 + l16;
      const float inv = 1.0f / (ls[nq] + LP[rowi]);
      float* og = Out + ((size_t)bh * S_ + qt * 64 + wq * 32 + nq * 16 + l16) * DK_;
      #pragma unroll
      for (int dblk = 0; dblk < 4; ++dblk) {
        const int c2 = (dblk * 4 + quad) ^ (l16 & 12);
        floatx4 tot = Ot[dblk][nq] + *(const floatx4*)&OP[rowi * 64 + c2 * 4];
        tot *= inv;
        *(floatx4*)(og + dblk * 16 + quad * 4) = tot;
      }
    }
  }
}

extern "C" void kernel_launch(void* const* d_in, const int* in_sizes, int n_in,
                              void* d_out, int out_size, void* d_ws, size_t ws_size,
                              hipStream_t stream) {
  const float* Q = (const float*)d_in[0];
  const float* K = (const float*)d_in[1];
  const float* V = (const float*)d_in[2];
  // d_in[3] = d_k (=64), d_in[4] = causal tril mask (applied analytically)
  float* Out = (float*)d_out;
  unsigned short* Kb = (unsigned short*)d_ws;                    // 8.4 MB
  unsigned short* Vb = Kb + (size_t)BH_ * S_ * DK_;              // 8.4 MB
  conv_kv<<<dim3(S_ / 64, BH_), 256, 0, stream>>>(K, V, Kb, Vb);
  fa_kernel<<<dim3(NQT * BH_), 256, 0, stream>>>(Q, Kb, Vb, Out);
}